// Round 1
// baseline (578.710 us; speedup 1.0000x reference)
//
#include <hip/hip_runtime.h>
#include <hip/hip_bf16.h>
#include <math.h>

#define B_ 4
#define N_ 512
#define D_ 128
#define O_ 64
#define H_ 4

// SELU constants
#define SELU_SCALE 1.0507009873554805f
#define SELU_SCALE_ALPHA 1.7580993408473766f  // scale * alpha

// Fused per-(b,i) attention kernel.
// Block = 256 threads (4 waves). Grid = (N, B). Each block computes one output
// row y[b,i,:] (pre-BN) into d_out.
//
// Math per block:
//   G[d,o]   = x[b,i,d] * Wa[d,o]                       (in LDS, in-place)
//   att[j,o] = tanh( sum_d x[b,j,d]*G[d,o] + ba[o] )
//   s[j,h]   = sum_o att[j,o]*AW[o,h]
//   p[:,h]   = softmax_j(s[:,h])
//   x1[d,h]  = sum_j p[j,h]*x[b,j,d]
//   y[o]     = sum_{d,h} x1[d,h]*PW[d*4+h,o] + PWb[o] + sum_d x[b,i,d]*NW[d,o] + NWb[o]
__global__ __launch_bounds__(256, 2) void attn_fused(
    const float* __restrict__ x,     // [B,N,D]
    const float* __restrict__ Wa,    // [D,O]
    const float* __restrict__ ba,    // [O]
    const float* __restrict__ AW,    // [O,H]
    const float* __restrict__ PW,    // [D*H,O]
    const float* __restrict__ PWb,   // [O]
    const float* __restrict__ NW,    // [D,O]
    const float* __restrict__ NWb,   // [O]
    float* __restrict__ y)           // [B*N,O]
{
    // LDS: 32K + 32K + 8K + 4K + small = 77.75 KB -> 2 blocks/CU
    __shared__ float sWt[O_ * D_];    // G^T, rows o, 16B-chunk XOR-swizzled by (o&7)
    __shared__ float sScr[64 * D_];   // x tile, rows r, chunk-swizzled by (r&7); later y partials
    __shared__ float sP[H_ * N_];     // scores -> probs, [h][j]
    __shared__ float sAmp[4 * H_ * 64]; // am partials [wave][h][j]; later x1 partials [2][512]
    __shared__ float sXi[D_];
    __shared__ float sAW[O_ * H_];
    __shared__ float sBias[O_];

    const int tid  = threadIdx.x;
    const int i    = blockIdx.x;
    const int b    = blockIdx.y;
    const int lane = tid & 63;
    const int wid  = tid >> 6;
    const float* xb = x + (size_t)b * N_ * D_;

    // ---- phase 0: load xi, W^T (transposed+swizzled), AW, bias ----
    if (tid < 32) {
        float4 v = *(const float4*)&xb[i * D_ + 4 * tid];
        *(float4*)&sXi[4 * tid] = v;
    }
    {
        const int o  = tid & 63;
        const int c0 = tid >> 6;
        #pragma unroll
        for (int p = 0; p < 8; ++p) {
            const int d4g = c0 + 4 * p;          // logical 4-dword chunk of d
            float4 wv;
            wv.x = Wa[(4 * d4g + 0) * O_ + o];
            wv.y = Wa[(4 * d4g + 1) * O_ + o];
            wv.z = Wa[(4 * d4g + 2) * O_ + o];
            wv.w = Wa[(4 * d4g + 3) * O_ + o];
            const int slot = d4g ^ (o & 7);
            *(float4*)&sWt[o * D_ + 4 * slot] = wv;
        }
        sAW[tid] = AW[tid];                      // 256 = O_*H_ exactly
        if (tid < 64) sBias[tid] = ba[tid];
    }
    __syncthreads();

    // ---- phase 0b: G = W^T * diag(xi), in place ----
    {
        const int o  = tid & 63;
        const int c0 = tid >> 6;
        #pragma unroll
        for (int p = 0; p < 8; ++p) {
            const int slot = c0 + 4 * p;
            const int q    = slot ^ (o & 7);     // logical chunk stored in this slot
            float4 v = *(float4*)&sWt[o * D_ + 4 * slot];
            v.x *= sXi[4 * q + 0];
            v.y *= sXi[4 * q + 1];
            v.z *= sXi[4 * q + 2];
            v.w *= sXi[4 * q + 3];
            *(float4*)&sWt[o * D_ + 4 * slot] = v;
        }
    }
    __syncthreads();

    // ---- phase 1: score tiles. lane = j within tile, wave owns 16 o's ----
    for (int jt = 0; jt < 8; ++jt) {
        // stage 64x128 x-tile, chunk-swizzled so per-lane row reads are conflict-free
        #pragma unroll
        for (int p = 0; p < 8; ++p) {
            const int m = p * 256 + tid;         // chunk id 0..2047
            const int r = m >> 5, c = m & 31;
            float4 v = *(const float4*)&xb[(jt * 64 + r) * D_ + 4 * (c ^ (r & 7))];
            *(float4*)&sScr[r * D_ + 4 * c] = v;
        }
        __syncthreads();

        float acc[16];
        #pragma unroll
        for (int oo = 0; oo < 16; ++oo) acc[oo] = 0.f;

        #pragma unroll 4
        for (int d4 = 0; d4 < 32; ++d4) {
            const float4 pj = *(const float4*)&sScr[lane * D_ + 4 * (d4 ^ (lane & 7))];
            #pragma unroll
            for (int oo = 0; oo < 16; ++oo) {
                const int o = wid * 16 + oo;     // o&7 == oo&7
                const float4 wv = *(const float4*)&sWt[o * D_ + 4 * (d4 ^ (oo & 7))];
                acc[oo] = fmaf(pj.x, wv.x, acc[oo]);
                acc[oo] = fmaf(pj.y, wv.y, acc[oo]);
                acc[oo] = fmaf(pj.z, wv.z, acc[oo]);
                acc[oo] = fmaf(pj.w, wv.w, acc[oo]);
            }
        }

        // tanh + in-register reduction over this wave's 16 o's
        float am0 = 0.f, am1 = 0.f, am2 = 0.f, am3 = 0.f;
        #pragma unroll
        for (int oo = 0; oo < 16; ++oo) {
            const int o = wid * 16 + oo;
            const float e   = __expf(2.f * (acc[oo] + sBias[o]));
            const float att = 1.f - 2.f / (e + 1.f);   // tanh
            am0 = fmaf(att, sAW[o * 4 + 0], am0);
            am1 = fmaf(att, sAW[o * 4 + 1], am1);
            am2 = fmaf(att, sAW[o * 4 + 2], am2);
            am3 = fmaf(att, sAW[o * 4 + 3], am3);
        }
        sAmp[wid * 256 + 0 * 64 + lane] = am0;
        sAmp[wid * 256 + 1 * 64 + lane] = am1;
        sAmp[wid * 256 + 2 * 64 + lane] = am2;
        sAmp[wid * 256 + 3 * 64 + lane] = am3;
        __syncthreads();

        // combine 4 wave-partials -> logits sP[h][jt*64+j]
        {
            const int h = tid >> 6, j = tid & 63;
            const float s = sAmp[h * 64 + j] + sAmp[256 + h * 64 + j] +
                            sAmp[512 + h * 64 + j] + sAmp[768 + h * 64 + j];
            sP[h * N_ + jt * 64 + j] = s;
        }
        __syncthreads();
    }

    // ---- phase 2: softmax over j, one wave per head ----
    {
        const int h = wid;
        float v[8];
        float m = -INFINITY;
        #pragma unroll
        for (int k = 0; k < 8; ++k) {
            v[k] = sP[h * N_ + k * 64 + lane];
            m = fmaxf(m, v[k]);
        }
        #pragma unroll
        for (int s = 32; s >= 1; s >>= 1) m = fmaxf(m, __shfl_xor(m, s));
        float l = 0.f;
        #pragma unroll
        for (int k = 0; k < 8; ++k) {
            v[k] = __expf(v[k] - m);
            l += v[k];
        }
        #pragma unroll
        for (int s = 32; s >= 1; s >>= 1) l += __shfl_xor(l, s);
        const float rinv = 1.f / l;
        #pragma unroll
        for (int k = 0; k < 8; ++k) sP[h * N_ + k * 64 + lane] = v[k] * rinv;
    }
    __syncthreads();

    // ---- phase 3: aggregation x1[d,h] = sum_j p[j,h]*x[b,j,d] ----
    float* sX1p = sAmp;   // reuse as [2][512] partials over j-halves
    {
        const int d4   = tid & 31;
        const int h    = (tid >> 5) & 3;
        const int half = tid >> 7;
        float a0 = 0.f, a1 = 0.f, a2 = 0.f, a3 = 0.f;
        const int j0 = half * 256;
        #pragma unroll 4
        for (int jj = 0; jj < 256; ++jj) {
            const int j = j0 + jj;
            const float4 xv = *(const float4*)&xb[j * D_ + 4 * d4];
            const float p = sP[h * N_ + j];
            a0 = fmaf(p, xv.x, a0);
            a1 = fmaf(p, xv.y, a1);
            a2 = fmaf(p, xv.z, a2);
            a3 = fmaf(p, xv.w, a3);
        }
        // x1 logical layout: dh = d*4 + h, d = 4*d4+k
        sX1p[half * 512 + 16 * d4 + 0  + h] = a0;
        sX1p[half * 512 + 16 * d4 + 4  + h] = a1;
        sX1p[half * 512 + 16 * d4 + 8  + h] = a2;
        sX1p[half * 512 + 16 * d4 + 12 + h] = a3;
    }
    __syncthreads();

    // ---- phase 4: output projections ----
    float* sYp = sScr;    // reuse as [4][64] partials
    {
        const int o = tid & 63, q = tid >> 6;
        float acc = 0.f;
        #pragma unroll 4
        for (int rr = 0; rr < 128; ++rr) {
            const int r = q * 128 + rr;          // dh index
            const float x1v = sX1p[r] + sX1p[512 + r];
            acc = fmaf(x1v, PW[r * O_ + o], acc);
        }
        #pragma unroll 4
        for (int dd = 0; dd < 32; ++dd) {
            const int d = q * 32 + dd;
            acc = fmaf(sXi[d], NW[d * O_ + o], acc);
        }
        sYp[q * 64 + o] = acc;
    }
    __syncthreads();
    if (tid < 64) {
        const float yv = sYp[tid] + sYp[64 + tid] + sYp[128 + tid] + sYp[192 + tid]
                       + PWb[tid] + NWb[tid];
        y[((size_t)b * N_ + i) * O_ + tid] = yv;
    }
}

// BatchNorm statistics: one block per output column o.
// Writes stats[o] = gamma*rstd (scale), stats[64+o] = beta - mu*scale (shift).
__global__ __launch_bounds__(256) void bn_stats(
    const float* __restrict__ y, float* __restrict__ stats,
    const float* __restrict__ gamma, const float* __restrict__ beta)
{
    const int o = blockIdx.x, t = threadIdx.x;
    float s = 0.f, s2 = 0.f;
    for (int r = t; r < B_ * N_; r += 256) {
        const float v = y[r * O_ + o];
        s += v;
        s2 += v * v;
    }
    __shared__ float rs[256], rq[256];
    rs[t] = s; rq[t] = s2;
    __syncthreads();
    for (int k = 128; k >= 1; k >>= 1) {
        if (t < k) { rs[t] += rs[t + k]; rq[t] += rq[t + k]; }
        __syncthreads();
    }
    if (t == 0) {
        const float inv = 1.f / (float)(B_ * N_);
        const float mu  = rs[0] * inv;
        const float var = rq[0] * inv - mu * mu;   // biased, matches jnp.var
        const float rstd = rsqrtf(var + 1e-5f);
        const float sc = gamma[o] * rstd;
        stats[o]      = sc;
        stats[64 + o] = beta[o] - mu * sc;
    }
}

// Normalize + SELU, in place on y (= d_out). 128 blocks x 256 threads x float4.
__global__ __launch_bounds__(256) void bn_apply(
    float* __restrict__ y, const float* __restrict__ stats)
{
    const int idx = blockIdx.x * 256 + threadIdx.x;  // index in float4 units
    float4 v = *(float4*)&y[idx * 4];
    const int o0 = (idx * 4) & 63;                   // 64 % 4 == 0: no row crossing
    float t0 = v.x * stats[o0 + 0] + stats[64 + o0 + 0];
    float t1 = v.y * stats[o0 + 1] + stats[64 + o0 + 1];
    float t2 = v.z * stats[o0 + 2] + stats[64 + o0 + 2];
    float t3 = v.w * stats[o0 + 3] + stats[64 + o0 + 3];
    v.x = t0 > 0.f ? SELU_SCALE * t0 : SELU_SCALE_ALPHA * (__expf(t0) - 1.f);
    v.y = t1 > 0.f ? SELU_SCALE * t1 : SELU_SCALE_ALPHA * (__expf(t1) - 1.f);
    v.z = t2 > 0.f ? SELU_SCALE * t2 : SELU_SCALE_ALPHA * (__expf(t2) - 1.f);
    v.w = t3 > 0.f ? SELU_SCALE * t3 : SELU_SCALE_ALPHA * (__expf(t3) - 1.f);
    *(float4*)&y[idx * 4] = v;
}

extern "C" void kernel_launch(void* const* d_in, const int* in_sizes, int n_in,
                              void* d_out, int out_size, void* d_ws, size_t ws_size,
                              hipStream_t stream)
{
    (void)in_sizes; (void)n_in; (void)out_size; (void)ws_size;
    const float* x     = (const float*)d_in[0];
    const float* Wa    = (const float*)d_in[1];
    const float* ba    = (const float*)d_in[2];
    const float* AW    = (const float*)d_in[3];
    const float* PW    = (const float*)d_in[4];
    const float* PWb   = (const float*)d_in[5];
    const float* NW    = (const float*)d_in[6];
    const float* NWb   = (const float*)d_in[7];
    const float* gamma = (const float*)d_in[8];
    const float* beta  = (const float*)d_in[9];

    float* y     = (float*)d_out;   // y (pre-BN) lives in d_out, finalized in place
    float* stats = (float*)d_ws;    // 128 floats: scale[64], shift[64]

    attn_fused<<<dim3(N_, B_), 256, 0, stream>>>(x, Wa, ba, AW, PW, PWb, NW, NWb, y);
    bn_stats<<<64, 256, 0, stream>>>(y, stats, gamma, beta);
    bn_apply<<<128, 256, 0, stream>>>(y, stats);
}

// Round 2
// 158.863 us; speedup vs baseline: 3.6428x; 3.6428x over previous
//
#include <hip/hip_runtime.h>
#include <hip/hip_bf16.h>
#include <math.h>

#define B_ 4
#define N_ 512
#define D_ 128
#define O_ 64
#define H_ 4

#define SELU_SCALE 1.0507009873554805f
#define SELU_SCALE_ALPHA 1.7580993408473766f  // scale * alpha

typedef short  short8 __attribute__((ext_vector_type(8)));
typedef float  f32x4  __attribute__((ext_vector_type(4)));

__device__ __forceinline__ ushort bf16rne(float f) {
    uint u = __float_as_uint(f);
    return (ushort)((u + 0x7fffu + ((u >> 16) & 1u)) >> 16);
}
__device__ __forceinline__ void bf16split(float f, ushort& h, ushort& l) {
    h = bf16rne(f);
    float hf = __uint_as_float(((uint)h) << 16);
    l = bf16rne(f - hf);
}

// ---------------------------------------------------------------------------
// Kernel 0: build bf16 hi/lo B-fragments of x in fragment-linear layout.
// frag id fi = ((b*32 + jf)*4 + kc)*2 + split ; each frag = 64 lanes x 16B.
// lane l holds x[b][jf*16 + (l&15)][kc*32 + (l>>4)*8 + e], e=0..7.
// Total: 1024 frags x 1KB = 1MB in d_ws.
// ---------------------------------------------------------------------------
__global__ __launch_bounds__(256) void make_xfrag(
    const float* __restrict__ x, ushort* __restrict__ xf)
{
    const int t   = blockIdx.x * 256 + threadIdx.x;  // 0..32767
    const int jg  = t >> 4;                          // b*512 + j
    const int dc  = t & 15;                          // 8-elem chunk of d
    const int jf  = jg >> 4;                         // = b*32 + (j>>4)
    const int kc  = dc >> 2, q = dc & 3;
    const int lane = (jg & 15) | (q << 4);

    const f32x4 v0 = *(const f32x4*)&x[t * 8];
    const f32x4 v1 = *(const f32x4*)&x[t * 8 + 4];
    float vv[8] = {v0[0], v0[1], v0[2], v0[3], v1[0], v1[1], v1[2], v1[3]};

    short8 h8, l8;
    #pragma unroll
    for (int e = 0; e < 8; ++e) {
        ushort h, l;
        bf16split(vv[e], h, l);
        h8[e] = (short)h;
        l8[e] = (short)l;
    }
    const int fi = (jf * 4 + kc) * 2;
    *(short8*)&xf[(size_t)fi * 512 + lane * 8]       = h8;
    *(short8*)&xf[(size_t)(fi + 1) * 512 + lane * 8] = l8;
}

// ---------------------------------------------------------------------------
// Kernel 1: fused per-(b,i) attention via MFMA.
//   Gt[o][d] = x_i[d]*Wa[d][o]  (bf16 hi/lo, LDS, granule-XOR-swizzled)
//   S^T[o][j] = Gt . x^T  via mfma_f32_16x16x32_bf16 (3-term bf16 split)
//   att=tanh(S+b); am[j,h]=att.AW (in-lane); softmax_j; x1=p.x; projections.
// ---------------------------------------------------------------------------
__global__ __launch_bounds__(256, 2) void attn_fused(
    const float* __restrict__ x,      // [B,N,D] fp32
    const ushort* __restrict__ xf,    // fragment tensor (ws)
    const float* __restrict__ Wa,     // [D,O]
    const float* __restrict__ ba,     // [O]
    const float* __restrict__ AW,     // [O,H]
    const float* __restrict__ PW,     // [D*H,O]
    const float* __restrict__ PWb,    // [O]
    const float* __restrict__ NW,     // [D,O]
    const float* __restrict__ NWb,    // [O]
    float* __restrict__ y)            // [B*N,O]
{
    __shared__ ushort sGt[2][64 * 128];  // 32KB; reused as px1[8][512] in phase 3
    __shared__ float  sP[4 * 512];       // logits -> probs [h][j]
    __shared__ float  sXi[128];
    __shared__ float  sAWf[256];         // AW [o][h]
    __shared__ float  sBias[64];
    __shared__ float  sX1[512];          // x1[dh]
    __shared__ float  sYp[256];          // y partials [q][o]

    const int tid  = threadIdx.x;
    const int i    = blockIdx.x;
    const int bB   = blockIdx.y;
    const int lane = tid & 63;
    const int w    = tid >> 6;
    const int l15  = lane & 15;
    const int q4   = lane >> 4;
    const float* xb = x + (size_t)bB * N_ * D_;

    // ---- phase 0: small loads ----
    if (tid < 32) {
        f32x4 v = *(const f32x4*)&xb[i * D_ + 4 * tid];
        *(f32x4*)&sXi[4 * tid] = v;
    }
    sAWf[tid] = AW[tid];
    if (tid < 64) sBias[tid] = ba[tid];
    __syncthreads();

    // ---- phase 0b: build Gt = (diag(x_i)*Wa)^T, bf16 split, swizzled ----
    {
        const int o = tid & 63, q = tid >> 6;
        #pragma unroll
        for (int dd = 0; dd < 16; ++dd) {
            const int d0 = q * 32 + dd * 2;
            const float g0 = sXi[d0]     * Wa[d0 * O_ + o];
            const float g1 = sXi[d0 + 1] * Wa[(d0 + 1) * O_ + o];
            ushort h0, l0, h1, l1;
            bf16split(g0, h0, l0);
            bf16split(g1, h1, l1);
            const int slot = (d0 >> 3) ^ (o & 15);
            const int pos  = o * 128 + slot * 8 + (d0 & 7);
            *(uint*)&sGt[0][pos] = (uint)h0 | ((uint)h1 << 16);
            *(uint*)&sGt[1][pos] = (uint)l0 | ((uint)l1 << 16);
        }
    }
    __syncthreads();

    // ---- phase 1: S^T = Gt . x^T with MFMA ----
    // A-frags (Gt) cached in registers: 4 of x 4 kc x {hi,lo}
    short8 gth[4][4], gtl[4][4];
    #pragma unroll
    for (int of = 0; of < 4; ++of) {
        #pragma unroll
        for (int kc = 0; kc < 4; ++kc) {
            const int row  = of * 16 + l15;
            const int slot = (kc * 4 + q4) ^ l15;
            gth[of][kc] = *(const short8*)&sGt[0][row * 128 + slot * 8];
            gtl[of][kc] = *(const short8*)&sGt[1][row * 128 + slot * 8];
        }
    }

    for (int ji = 0; ji < 8; ++ji) {
        const int jf = w * 8 + ji;   // block-local j-fragment 0..31
        const ushort* bp = xf + ((size_t)(bB * 32 + jf) * 8) * 512;

        short8 bh[4], bl[4];
        #pragma unroll
        for (int kc = 0; kc < 4; ++kc) {
            bh[kc] = *(const short8*)&bp[kc * 1024 + lane * 8];
            bl[kc] = *(const short8*)&bp[kc * 1024 + 512 + lane * 8];
        }

        f32x4 acc[4];
        const f32x4 z = {0.f, 0.f, 0.f, 0.f};
        #pragma unroll
        for (int of = 0; of < 4; ++of) acc[of] = z;

        #pragma unroll
        for (int kc = 0; kc < 4; ++kc) {
            #pragma unroll
            for (int of = 0; of < 4; ++of) {
                acc[of] = __builtin_amdgcn_mfma_f32_16x16x32_bf16(gth[of][kc], bh[kc], acc[of], 0, 0, 0);
                acc[of] = __builtin_amdgcn_mfma_f32_16x16x32_bf16(gtl[of][kc], bh[kc], acc[of], 0, 0, 0);
                acc[of] = __builtin_amdgcn_mfma_f32_16x16x32_bf16(gth[of][kc], bl[kc], acc[of], 0, 0, 0);
            }
        }

        // epilogue: tanh + am (in-lane over this lane's 16 o's), reduce groups
        float am0 = 0.f, am1 = 0.f, am2 = 0.f, am3 = 0.f;
        #pragma unroll
        for (int of = 0; of < 4; ++of) {
            #pragma unroll
            for (int r = 0; r < 4; ++r) {
                const int o = of * 16 + q4 * 4 + r;
                const float sc = acc[of][r] + sBias[o];
                const float e = __expf(2.f * sc);
                const float att = 1.f - 2.f / (e + 1.f);
                const f32x4 aw = *(const f32x4*)&sAWf[o * 4];
                am0 = fmaf(att, aw[0], am0);
                am1 = fmaf(att, aw[1], am1);
                am2 = fmaf(att, aw[2], am2);
                am3 = fmaf(att, aw[3], am3);
            }
        }
        am0 += __shfl_xor(am0, 16); am0 += __shfl_xor(am0, 32);
        am1 += __shfl_xor(am1, 16); am1 += __shfl_xor(am1, 32);
        am2 += __shfl_xor(am2, 16); am2 += __shfl_xor(am2, 32);
        am3 += __shfl_xor(am3, 16); am3 += __shfl_xor(am3, 32);
        const float amsel = (q4 == 0) ? am0 : (q4 == 1) ? am1 : (q4 == 2) ? am2 : am3;
        sP[q4 * 512 + jf * 16 + l15] = amsel;
    }
    __syncthreads();

    // ---- phase 2: softmax over j, one wave per head ----
    {
        const int h = w;
        float v[8];
        float m = -INFINITY;
        #pragma unroll
        for (int k = 0; k < 8; ++k) {
            v[k] = sP[h * N_ + k * 64 + lane];
            m = fmaxf(m, v[k]);
        }
        #pragma unroll
        for (int s = 32; s >= 1; s >>= 1) m = fmaxf(m, __shfl_xor(m, s));
        float l = 0.f;
        #pragma unroll
        for (int k = 0; k < 8; ++k) { v[k] = __expf(v[k] - m); l += v[k]; }
        #pragma unroll
        for (int s = 32; s >= 1; s >>= 1) l += __shfl_xor(l, s);
        const float rinv = 1.f / l;
        #pragma unroll
        for (int k = 0; k < 8; ++k) sP[h * N_ + k * 64 + lane] = v[k] * rinv;
    }
    __syncthreads();

    // ---- phase 3: x1[d,h] = sum_j p[j,h]*x[b,j,d]; thread = (d4, jgroup) ----
    {
        const int d4 = tid & 31, jg = tid >> 5;
        f32x4 a0 = {0,0,0,0}, a1 = a0, a2 = a0, a3 = a0;
        const float* xcol = xb + d4 * 4;
        #pragma unroll 2
        for (int jj = 0; jj < 64; ++jj) {
            const int j = jg * 64 + jj;
            const f32x4 xv = *(const f32x4*)&xcol[j * D_];
            const float p0 = sP[j], p1 = sP[512 + j], p2 = sP[1024 + j], p3 = sP[1536 + j];
            #pragma unroll
            for (int k = 0; k < 4; ++k) {
                a0[k] = fmaf(p0, xv[k], a0[k]);
                a1[k] = fmaf(p1, xv[k], a1[k]);
                a2[k] = fmaf(p2, xv[k], a2[k]);
                a3[k] = fmaf(p3, xv[k], a3[k]);
            }
        }
        float* px1 = (float*)sGt;  // [8][512], Gt no longer needed
        #pragma unroll
        for (int k = 0; k < 4; ++k) {
            const int dh = (d4 * 4 + k) * 4;
            px1[jg * 512 + dh + 0] = a0[k];
            px1[jg * 512 + dh + 1] = a1[k];
            px1[jg * 512 + dh + 2] = a2[k];
            px1[jg * 512 + dh + 3] = a3[k];
        }
    }
    __syncthreads();

    // pre-reduce 8 partials -> sX1[dh]
    {
        const float* px1 = (const float*)sGt;
        #pragma unroll
        for (int rep = 0; rep < 2; ++rep) {
            const int dh = rep * 256 + tid;
            float s = 0.f;
            #pragma unroll
            for (int g = 0; g < 8; ++g) s += px1[g * 512 + dh];
            sX1[dh] = s;
        }
    }
    __syncthreads();

    // ---- phase 4: output projections ----
    {
        const int o = tid & 63, q = tid >> 6;
        float acc = 0.f;
        #pragma unroll 4
        for (int rr = 0; rr < 128; ++rr) {
            const int r = q * 128 + rr;
            acc = fmaf(sX1[r], PW[r * O_ + o], acc);
        }
        #pragma unroll 4
        for (int dd = 0; dd < 32; ++dd) {
            const int d = q * 32 + dd;
            acc = fmaf(sXi[d], NW[d * O_ + o], acc);
        }
        sYp[q * 64 + o] = acc;
    }
    __syncthreads();
    if (tid < 64) {
        const float yv = sYp[tid] + sYp[64 + tid] + sYp[128 + tid] + sYp[192 + tid]
                       + PWb[tid] + NWb[tid];
        y[((size_t)bB * N_ + i) * O_ + tid] = yv;
    }
}

// ---------------------------------------------------------------------------
// BatchNorm stats + apply (unchanged from round 1)
// ---------------------------------------------------------------------------
__global__ __launch_bounds__(256) void bn_stats(
    const float* __restrict__ y, float* __restrict__ stats,
    const float* __restrict__ gamma, const float* __restrict__ beta)
{
    const int o = blockIdx.x, t = threadIdx.x;
    float s = 0.f, s2 = 0.f;
    for (int r = t; r < B_ * N_; r += 256) {
        const float v = y[r * O_ + o];
        s += v;
        s2 += v * v;
    }
    __shared__ float rs[256], rq[256];
    rs[t] = s; rq[t] = s2;
    __syncthreads();
    for (int k = 128; k >= 1; k >>= 1) {
        if (t < k) { rs[t] += rs[t + k]; rq[t] += rq[t + k]; }
        __syncthreads();
    }
    if (t == 0) {
        const float inv = 1.f / (float)(B_ * N_);
        const float mu  = rs[0] * inv;
        const float var = rq[0] * inv - mu * mu;
        const float rstd = rsqrtf(var + 1e-5f);
        const float sc = gamma[o] * rstd;
        stats[o]      = sc;
        stats[64 + o] = beta[o] - mu * sc;
    }
}

__global__ __launch_bounds__(256) void bn_apply(
    float* __restrict__ y, const float* __restrict__ stats)
{
    const int idx = blockIdx.x * 256 + threadIdx.x;
    f32x4 v = *(f32x4*)&y[idx * 4];
    const int o0 = (idx * 4) & 63;
    #pragma unroll
    for (int k = 0; k < 4; ++k) {
        const float t = v[k] * stats[o0 + k] + stats[64 + o0 + k];
        v[k] = t > 0.f ? SELU_SCALE * t : SELU_SCALE_ALPHA * (__expf(t) - 1.f);
    }
    *(f32x4*)&y[idx * 4] = v;
}

extern "C" void kernel_launch(void* const* d_in, const int* in_sizes, int n_in,
                              void* d_out, int out_size, void* d_ws, size_t ws_size,
                              hipStream_t stream)
{
    (void)in_sizes; (void)n_in; (void)out_size; (void)ws_size;
    const float* x     = (const float*)d_in[0];
    const float* Wa    = (const float*)d_in[1];
    const float* ba    = (const float*)d_in[2];
    const float* AW    = (const float*)d_in[3];
    const float* PW    = (const float*)d_in[4];
    const float* PWb   = (const float*)d_in[5];
    const float* NW    = (const float*)d_in[6];
    const float* NWb   = (const float*)d_in[7];
    const float* gamma = (const float*)d_in[8];
    const float* beta  = (const float*)d_in[9];

    ushort* xfrag = (ushort*)d_ws;                       // 1 MB
    float*  stats = (float*)((char*)d_ws + (1 << 20));   // 128 floats
    float*  y     = (float*)d_out;

    make_xfrag<<<128, 256, 0, stream>>>(x, xfrag);
    attn_fused<<<dim3(N_, B_), 256, 0, stream>>>(x, xfrag, Wa, ba, AW, PW, PWb, NW, NWb, y);
    bn_stats<<<64, 256, 0, stream>>>(y, stats, gamma, beta);
    bn_apply<<<128, 256, 0, stream>>>(y, stats);
}

// Round 3
// 125.770 us; speedup vs baseline: 4.6013x; 1.2631x over previous
//
#include <hip/hip_runtime.h>
#include <hip/hip_bf16.h>
#include <math.h>

#define B_ 4
#define N_ 512
#define D_ 128
#define O_ 64
#define H_ 4

#define SELU_SCALE 1.0507009873554805f
#define SELU_SCALE_ALPHA 1.7580993408473766f  // scale * alpha

typedef short  short8 __attribute__((ext_vector_type(8)));
typedef float  f32x4  __attribute__((ext_vector_type(4)));

__device__ __forceinline__ ushort bf16rne(float f) {
    uint u = __float_as_uint(f);
    return (ushort)((u + 0x7fffu + ((u >> 16) & 1u)) >> 16);
}
__device__ __forceinline__ void bf16split(float f, ushort& h, ushort& l) {
    h = bf16rne(f);
    float hf = __uint_as_float(((uint)h) << 16);
    l = bf16rne(f - hf);
}

// ---------------------------------------------------------------------------
// prep_frags: one kernel, four independent jobs by blockIdx range.
//  A (blk 0..127):   xf  — x B/A-frags, K=d orient. fi=((b*32+jf)*4+kc)*2+s
//  B (blk 128..255): xfT — x B-frags,   K=j orient. fi=((b*16+kc)*8+d0)*2+s
//  C (blk 256..271): pwf — PW' B-frags (kappa=(h,d) reindex). fi=(kc*4+o0)*2+s
//  D (blk 272..275): nwf — NW  B-frags. fi=(kc*4+o0)*2+s
// Every frag: 64 lanes x 8 bf16 = 512 ushort = 1 KB.
// ---------------------------------------------------------------------------
__global__ __launch_bounds__(256) void prep_frags(
    const float* __restrict__ x, const float* __restrict__ PW,
    const float* __restrict__ NW,
    ushort* __restrict__ xf, ushort* __restrict__ xfT,
    ushort* __restrict__ pwf, ushort* __restrict__ nwf)
{
    const int bid = blockIdx.x;
    const int tid = threadIdx.x;

    if (bid < 128) {
        const int t  = bid * 256 + tid;              // 0..32767
        const int jg = t >> 4;                       // b*512 + j
        const int dc = t & 15;
        const int jf = jg >> 4;                      // b*32 + (j>>4)
        const int kc = dc >> 2, q = dc & 3;
        const int lane = (jg & 15) | (q << 4);

        const f32x4 v0 = *(const f32x4*)&x[t * 8];
        const f32x4 v1 = *(const f32x4*)&x[t * 8 + 4];
        float vv[8] = {v0[0], v0[1], v0[2], v0[3], v1[0], v1[1], v1[2], v1[3]};
        short8 h8, l8;
        #pragma unroll
        for (int e = 0; e < 8; ++e) {
            ushort h, l; bf16split(vv[e], h, l);
            h8[e] = (short)h; l8[e] = (short)l;
        }
        const int fi = (jf * 4 + kc) * 2;
        *(short8*)&xf[(size_t)fi * 512 + lane * 8]       = h8;
        *(short8*)&xf[(size_t)(fi + 1) * 512 + lane * 8] = l8;
    } else if (bid < 256) {
        const int t    = (bid - 128) * 256 + tid;    // 0..32767
        const int lane = t & 63, fr = t >> 6;        // fr 0..511
        const int d0 = fr & 7, kc = (fr >> 3) & 15, b = fr >> 7;
        const int l15 = lane & 15, q4 = lane >> 4;
        short8 h8, l8;
        #pragma unroll
        for (int e = 0; e < 8; ++e) {
            const float v = x[(size_t)((b * 512) + kc * 32 + q4 * 8 + e) * 128 + d0 * 16 + l15];
            ushort h, l; bf16split(v, h, l);
            h8[e] = (short)h; l8[e] = (short)l;
        }
        *(short8*)&xfT[(size_t)(fr * 2) * 512 + lane * 8]     = h8;
        *(short8*)&xfT[(size_t)(fr * 2 + 1) * 512 + lane * 8] = l8;
    } else if (bid < 272) {
        const int t    = (bid - 256) * 256 + tid;    // 0..4095
        const int lane = t & 63, fr = t >> 6;        // fr 0..63
        const int o0 = fr & 3, kc = fr >> 2;         // kc 0..15
        const int l15 = lane & 15, q4 = lane >> 4;
        short8 h8, l8;
        #pragma unroll
        for (int e = 0; e < 8; ++e) {
            const int kk = kc * 32 + q4 * 8 + e;     // kappa = h*128 + d
            const int d = kk & 127, h = kk >> 7;
            const float v = PW[(d * 4 + h) * O_ + o0 * 16 + l15];
            ushort hh, ll; bf16split(v, hh, ll);
            h8[e] = (short)hh; l8[e] = (short)ll;
        }
        *(short8*)&pwf[(size_t)(fr * 2) * 512 + lane * 8]     = h8;
        *(short8*)&pwf[(size_t)(fr * 2 + 1) * 512 + lane * 8] = l8;
    } else {
        const int t    = (bid - 272) * 256 + tid;    // 0..1023
        const int lane = t & 63, fr = t >> 6;        // fr 0..15
        const int o0 = fr & 3, kc = fr >> 2;         // kc 0..3
        const int l15 = lane & 15, q4 = lane >> 4;
        short8 h8, l8;
        #pragma unroll
        for (int e = 0; e < 8; ++e) {
            const float v = NW[(kc * 32 + q4 * 8 + e) * O_ + o0 * 16 + l15];
            ushort hh, ll; bf16split(v, hh, ll);
            h8[e] = (short)hh; l8[e] = (short)ll;
        }
        *(short8*)&nwf[(size_t)(fr * 2) * 512 + lane * 8]     = h8;
        *(short8*)&nwf[(size_t)(fr * 2 + 1) * 512 + lane * 8] = l8;
    }
}

// ---------------------------------------------------------------------------
// attn_scores: per-(b,i) fused scores -> softmax -> MFMA aggregation.
// Writes x1[bi][kappa=(h*128+d)] as bf16 hi/lo tensors X1h/X1l.
// ---------------------------------------------------------------------------
__global__ __launch_bounds__(256, 2) void attn_scores(
    const float* __restrict__ x,      // [B,N,D]
    const ushort* __restrict__ xf,    // K=d frags
    const ushort* __restrict__ xfT,   // K=j frags
    const float* __restrict__ Wa,     // [D,O]
    const float* __restrict__ ba,     // [O]
    const float* __restrict__ AW,     // [O,H]
    ushort* __restrict__ X1h, ushort* __restrict__ X1l)  // [2048,512] bf16
{
    __shared__ ushort sGt[2 * 8192];   // 32 KB G^T hi/lo; reused as sXp f32[2048]
    __shared__ float  sP[4 * 512];     // logits -> probs [h][j]
    __shared__ float  sXi[128];
    __shared__ float  sAWf[256];
    __shared__ float  sBias[64];

    const int tid  = threadIdx.x;
    const int i    = blockIdx.x;
    const int bB   = blockIdx.y;
    const int lane = tid & 63;
    const int w    = tid >> 6;
    const int l15  = lane & 15;
    const int q4   = lane >> 4;
    const float* xb = x + (size_t)bB * N_ * D_;

    // ---- phase 0: issue Wa loads into regs FIRST (latency hidden), stage xi ----
    const int o = tid & 63, q = tid >> 6;
    float wv[32];
    #pragma unroll
    for (int dd = 0; dd < 16; ++dd) {
        const int d0 = q * 32 + dd * 2;
        wv[2 * dd]     = Wa[d0 * O_ + o];
        wv[2 * dd + 1] = Wa[(d0 + 1) * O_ + o];
    }
    if (tid < 32) {
        f32x4 v = *(const f32x4*)&xb[i * D_ + 4 * tid];
        *(f32x4*)&sXi[4 * tid] = v;
    }
    sAWf[tid] = AW[tid];
    if (tid < 64) sBias[tid] = ba[tid];
    __syncthreads();

    // ---- phase 0b: Gt = (diag(x_i)*Wa)^T, bf16 split, granule-swizzled ----
    #pragma unroll
    for (int dd = 0; dd < 16; ++dd) {
        const int d0 = q * 32 + dd * 2;
        const float g0 = sXi[d0]     * wv[2 * dd];
        const float g1 = sXi[d0 + 1] * wv[2 * dd + 1];
        ushort h0, l0, h1, l1;
        bf16split(g0, h0, l0);
        bf16split(g1, h1, l1);
        const int slot = (d0 >> 3) ^ (o & 15);
        const int pos  = o * 128 + slot * 8 + (d0 & 7);
        *(uint*)&sGt[pos]        = (uint)h0 | ((uint)h1 << 16);
        *(uint*)&sGt[8192 + pos] = (uint)l0 | ((uint)l1 << 16);
    }
    __syncthreads();

    // ---- A-frags for scores ----
    short8 gth[4][4], gtl[4][4];
    #pragma unroll
    for (int of = 0; of < 4; ++of) {
        #pragma unroll
        for (int kc = 0; kc < 4; ++kc) {
            const int row  = of * 16 + l15;
            const int slot = (kc * 4 + q4) ^ l15;
            gth[of][kc] = *(const short8*)&sGt[row * 128 + slot * 8];
            gtl[of][kc] = *(const short8*)&sGt[8192 + row * 128 + slot * 8];
        }
    }

    // ---- phase 1: S^T tiles, B double-buffered across unrolled ji ----
    short8 bh[2][4], bl[2][4];
    {
        const ushort* bp = xf + ((size_t)(bB * 32 + w * 8) * 8) * 512;
        #pragma unroll
        for (int kc = 0; kc < 4; ++kc) {
            bh[0][kc] = *(const short8*)&bp[kc * 1024 + lane * 8];
            bl[0][kc] = *(const short8*)&bp[kc * 1024 + 512 + lane * 8];
        }
    }
    #pragma unroll
    for (int ji = 0; ji < 8; ++ji) {
        const int cur = ji & 1, nxt = cur ^ 1;
        if (ji < 7) {
            const ushort* bp = xf + ((size_t)(bB * 32 + w * 8 + ji + 1) * 8) * 512;
            #pragma unroll
            for (int kc = 0; kc < 4; ++kc) {
                bh[nxt][kc] = *(const short8*)&bp[kc * 1024 + lane * 8];
                bl[nxt][kc] = *(const short8*)&bp[kc * 1024 + 512 + lane * 8];
            }
        }
        const int jf = w * 8 + ji;

        f32x4 acc[4];
        const f32x4 z = {0.f, 0.f, 0.f, 0.f};
        #pragma unroll
        for (int of = 0; of < 4; ++of) acc[of] = z;
        #pragma unroll
        for (int kc = 0; kc < 4; ++kc) {
            #pragma unroll
            for (int of = 0; of < 4; ++of) {
                acc[of] = __builtin_amdgcn_mfma_f32_16x16x32_bf16(gth[of][kc], bh[cur][kc], acc[of], 0, 0, 0);
                acc[of] = __builtin_amdgcn_mfma_f32_16x16x32_bf16(gtl[of][kc], bh[cur][kc], acc[of], 0, 0, 0);
                acc[of] = __builtin_amdgcn_mfma_f32_16x16x32_bf16(gth[of][kc], bl[cur][kc], acc[of], 0, 0, 0);
            }
        }

        // epilogue: tanh + am in-lane over 16 o's, reduce over q4 groups
        float am0 = 0.f, am1 = 0.f, am2 = 0.f, am3 = 0.f;
        #pragma unroll
        for (int of = 0; of < 4; ++of) {
            #pragma unroll
            for (int r = 0; r < 4; ++r) {
                const int oo = of * 16 + q4 * 4 + r;
                const float sc = acc[of][r] + sBias[oo];
                const float e = __expf(2.f * sc);
                const float att = 1.f - 2.f / (e + 1.f);
                const f32x4 aw = *(const f32x4*)&sAWf[oo * 4];
                am0 = fmaf(att, aw[0], am0);
                am1 = fmaf(att, aw[1], am1);
                am2 = fmaf(att, aw[2], am2);
                am3 = fmaf(att, aw[3], am3);
            }
        }
        am0 += __shfl_xor(am0, 16); am0 += __shfl_xor(am0, 32);
        am1 += __shfl_xor(am1, 16); am1 += __shfl_xor(am1, 32);
        am2 += __shfl_xor(am2, 16); am2 += __shfl_xor(am2, 32);
        am3 += __shfl_xor(am3, 16); am3 += __shfl_xor(am3, 32);
        const float amsel = (q4 == 0) ? am0 : (q4 == 1) ? am1 : (q4 == 2) ? am2 : am3;
        sP[q4 * 512 + jf * 16 + l15] = amsel;
    }
    __syncthreads();

    // ---- phase 2: softmax over j, one wave per head ----
    {
        const int h = w;
        float v[8];
        float m = -INFINITY;
        #pragma unroll
        for (int k = 0; k < 8; ++k) {
            v[k] = sP[h * N_ + k * 64 + lane];
            m = fmaxf(m, v[k]);
        }
        #pragma unroll
        for (int s = 32; s >= 1; s >>= 1) m = fmaxf(m, __shfl_xor(m, s));
        float l = 0.f;
        #pragma unroll
        for (int k = 0; k < 8; ++k) { v[k] = __expf(v[k] - m); l += v[k]; }
        #pragma unroll
        for (int s = 32; s >= 1; s >>= 1) l += __shfl_xor(l, s);
        const float rinv = 1.f / l;
        #pragma unroll
        for (int k = 0; k < 8; ++k) sP[h * N_ + k * 64 + lane] = v[k] * rinv;
    }
    __syncthreads();

    // ---- phase 3: aggregation as MFMA. A = P rows(h), B = xfT (K=j). ----
    // wave w covers kc = w*4 .. w*4+3 (j chunks); acc2[nf] = partial x1[h][d].
    f32x4 acc2[8];
    {
        const f32x4 z = {0.f, 0.f, 0.f, 0.f};
        #pragma unroll
        for (int nf = 0; nf < 8; ++nf) acc2[nf] = z;
    }
    #pragma unroll
    for (int c = 0; c < 4; ++c) {
        const int kc = w * 4 + c;
        const f32x4 p0 = *(const f32x4*)&sP[(l15 & 3) * 512 + kc * 32 + q4 * 8];
        const f32x4 p1 = *(const f32x4*)&sP[(l15 & 3) * 512 + kc * 32 + q4 * 8 + 4];
        float pv[8] = {p0[0], p0[1], p0[2], p0[3], p1[0], p1[1], p1[2], p1[3]};
        short8 pah, pal;
        #pragma unroll
        for (int e = 0; e < 8; ++e) {
            ushort h, l; bf16split(pv[e], h, l);
            pah[e] = (short)h; pal[e] = (short)l;
        }
        #pragma unroll
        for (int nf = 0; nf < 8; ++nf) {
            const size_t f2 = ((size_t)(bB * 16 + kc) * 8 + nf) * 2;
            const short8 xh = *(const short8*)&xfT[f2 * 512 + lane * 8];
            const short8 xl = *(const short8*)&xfT[(f2 + 1) * 512 + lane * 8];
            acc2[nf] = __builtin_amdgcn_mfma_f32_16x16x32_bf16(pah, xh, acc2[nf], 0, 0, 0);
            acc2[nf] = __builtin_amdgcn_mfma_f32_16x16x32_bf16(pal, xh, acc2[nf], 0, 0, 0);
            acc2[nf] = __builtin_amdgcn_mfma_f32_16x16x32_bf16(pah, xl, acc2[nf], 0, 0, 0);
        }
    }
    // valid C rows are h=0..3 <=> lanes 0..15 (q4==0)
    float* sXp = (float*)sGt;   // [4 waves][4 h][128 d]
    if (q4 == 0) {
        #pragma unroll
        for (int nf = 0; nf < 8; ++nf)
            #pragma unroll
            for (int r = 0; r < 4; ++r)
                sXp[(w * 4 + r) * 128 + nf * 16 + l15] = acc2[nf][r];
    }
    __syncthreads();

    // ---- phase 3b: reduce wave partials, split, store X1 ----
    {
        const int kap = tid * 2;                     // kappa pair
        const size_t row = (size_t)bB * 512 + i;
        float v0 = 0.f, v1 = 0.f;
        #pragma unroll
        for (int ww = 0; ww < 4; ++ww) {
            v0 += sXp[(ww * 4 + (kap >> 7)) * 128 + (kap & 127)];
            v1 += sXp[(ww * 4 + ((kap + 1) >> 7)) * 128 + ((kap + 1) & 127)];
        }
        ushort h0, l0, h1, l1;
        bf16split(v0, h0, l0);
        bf16split(v1, h1, l1);
        *(uint*)&X1h[row * 512 + kap] = (uint)h0 | ((uint)h1 << 16);
        *(uint*)&X1l[row * 512 + kap] = (uint)l0 | ((uint)l1 << 16);
    }
}

// ---------------------------------------------------------------------------
// proj_y: y[bi,o] = x1 . PW' + x . NW + biases, MFMA GEMM, 128 blocks x 16 rows.
// ---------------------------------------------------------------------------
__global__ __launch_bounds__(256) void proj_y(
    const ushort* __restrict__ X1h, const ushort* __restrict__ X1l,
    const ushort* __restrict__ xf,
    const ushort* __restrict__ pwf, const ushort* __restrict__ nwf,
    const float* __restrict__ PWb, const float* __restrict__ NWb,
    float* __restrict__ y)
{
    const int tid = threadIdx.x, bid = blockIdx.x;
    const int lane = tid & 63, w = tid >> 6;
    const int l15 = lane & 15, q4 = lane >> 4;
    const int bi0 = bid * 16;
    const int b = bi0 >> 9, ig = (bi0 >> 4) & 31;

    f32x4 acc = {0.f, 0.f, 0.f, 0.f};
    #pragma unroll
    for (int kc = 0; kc < 16; ++kc) {
        const size_t arow = (size_t)(bi0 + l15) * 512 + kc * 32 + q4 * 8;
        const short8 ah = *(const short8*)&X1h[arow];
        const short8 al = *(const short8*)&X1l[arow];
        const int f3 = (kc * 4 + w) * 2;
        const short8 bhv = *(const short8*)&pwf[(size_t)f3 * 512 + lane * 8];
        const short8 blv = *(const short8*)&pwf[(size_t)(f3 + 1) * 512 + lane * 8];
        acc = __builtin_amdgcn_mfma_f32_16x16x32_bf16(ah, bhv, acc, 0, 0, 0);
        acc = __builtin_amdgcn_mfma_f32_16x16x32_bf16(al, bhv, acc, 0, 0, 0);
        acc = __builtin_amdgcn_mfma_f32_16x16x32_bf16(ah, blv, acc, 0, 0, 0);
    }
    #pragma unroll
    for (int kc = 0; kc < 4; ++kc) {
        const size_t fi = ((size_t)(b * 32 + ig) * 4 + kc) * 2;
        const short8 ah = *(const short8*)&xf[fi * 512 + lane * 8];
        const short8 al = *(const short8*)&xf[(fi + 1) * 512 + lane * 8];
        const int f4 = (kc * 4 + w) * 2;
        const short8 bhv = *(const short8*)&nwf[(size_t)f4 * 512 + lane * 8];
        const short8 blv = *(const short8*)&nwf[(size_t)(f4 + 1) * 512 + lane * 8];
        acc = __builtin_amdgcn_mfma_f32_16x16x32_bf16(ah, bhv, acc, 0, 0, 0);
        acc = __builtin_amdgcn_mfma_f32_16x16x32_bf16(al, bhv, acc, 0, 0, 0);
        acc = __builtin_amdgcn_mfma_f32_16x16x32_bf16(ah, blv, acc, 0, 0, 0);
    }
    const int oo = w * 16 + l15;
    const float bias = PWb[oo] + NWb[oo];
    #pragma unroll
    for (int r = 0; r < 4; ++r)
        y[(size_t)(bi0 + q4 * 4 + r) * O_ + oo] = acc[r] + bias;
}

// ---------------------------------------------------------------------------
// BatchNorm: coalesced partial sums -> finalize -> apply+SELU
// ---------------------------------------------------------------------------
__global__ __launch_bounds__(256) void bn_partial(
    const float* __restrict__ y, float* __restrict__ part)
{
    const int bid = blockIdx.x, tid = threadIdx.x;
    const int o = tid & 63, rg = tid >> 6;
    float s = 0.f, s2 = 0.f;
    #pragma unroll
    for (int rr = 0; rr < 8; ++rr) {
        const float v = y[(size_t)(bid * 32 + rg * 8 + rr) * O_ + o];
        s += v; s2 += v * v;
    }
    __shared__ float ls[4][64], lq[4][64];
    ls[rg][o] = s; lq[rg][o] = s2;
    __syncthreads();
    if (tid < 64) {
        part[bid * 128 + tid]      = ls[0][tid] + ls[1][tid] + ls[2][tid] + ls[3][tid];
        part[bid * 128 + 64 + tid] = lq[0][tid] + lq[1][tid] + lq[2][tid] + lq[3][tid];
    }
}

__global__ __launch_bounds__(256) void bn_final(
    const float* __restrict__ part, const float* __restrict__ gamma,
    const float* __restrict__ beta, float* __restrict__ stats)
{
    const int tid = threadIdx.x, o = tid & 63, g = tid >> 6;
    float s = 0.f, s2 = 0.f;
    #pragma unroll
    for (int k = 0; k < 16; ++k) {
        s  += part[(g * 16 + k) * 128 + o];
        s2 += part[(g * 16 + k) * 128 + 64 + o];
    }
    __shared__ float ls[4][64], lq[4][64];
    ls[g][o] = s; lq[g][o] = s2;
    __syncthreads();
    if (tid < 64) {
        const float inv = 1.f / 2048.f;
        const float ts = ls[0][tid] + ls[1][tid] + ls[2][tid] + ls[3][tid];
        const float tq = lq[0][tid] + lq[1][tid] + lq[2][tid] + lq[3][tid];
        const float mu  = ts * inv;
        const float var = tq * inv - mu * mu;
        const float rstd = rsqrtf(var + 1e-5f);
        const float sc = gamma[tid] * rstd;
        stats[tid]      = sc;
        stats[64 + tid] = beta[tid] - mu * sc;
    }
}

__global__ __launch_bounds__(256) void bn_apply(
    float* __restrict__ y, const float* __restrict__ stats)
{
    const int idx = blockIdx.x * 256 + threadIdx.x;
    f32x4 v = *(f32x4*)&y[idx * 4];
    const int o0 = (idx * 4) & 63;
    #pragma unroll
    for (int k = 0; k < 4; ++k) {
        const float t = v[k] * stats[o0 + k] + stats[64 + o0 + k];
        v[k] = t > 0.f ? SELU_SCALE * t : SELU_SCALE_ALPHA * (__expf(t) - 1.f);
    }
    *(f32x4*)&y[idx * 4] = v;
}

extern "C" void kernel_launch(void* const* d_in, const int* in_sizes, int n_in,
                              void* d_out, int out_size, void* d_ws, size_t ws_size,
                              hipStream_t stream)
{
    (void)in_sizes; (void)n_in; (void)out_size; (void)ws_size;
    const float* x     = (const float*)d_in[0];
    const float* Wa    = (const float*)d_in[1];
    const float* ba    = (const float*)d_in[2];
    const float* AW    = (const float*)d_in[3];
    const float* PW    = (const float*)d_in[4];
    const float* PWb   = (const float*)d_in[5];
    const float* NW    = (const float*)d_in[6];
    const float* NWb   = (const float*)d_in[7];
    const float* gamma = (const float*)d_in[8];
    const float* beta  = (const float*)d_in[9];

    char* ws = (char*)d_ws;
    ushort* xf    = (ushort*)ws;                                   // 1 MB
    ushort* xfT   = (ushort*)(ws + (1 << 20));                     // 1 MB
    ushort* X1h   = (ushort*)(ws + (2 << 20));                     // 2 MB
    ushort* X1l   = (ushort*)(ws + (4 << 20));                     // 2 MB
    ushort* pwf   = (ushort*)(ws + (6 << 20));                     // 128 KB
    ushort* nwf   = (ushort*)(ws + (6 << 20) + (128 << 10));       // 32 KB
    float*  part  = (float*)(ws + (6 << 20) + (160 << 10));        // 32 KB
    float*  stats = (float*)(ws + (6 << 20) + (192 << 10));        // 512 B
    float*  y     = (float*)d_out;

    prep_frags<<<276, 256, 0, stream>>>(x, PW, NW, xf, xfT, pwf, nwf);
    attn_scores<<<dim3(N_, B_), 256, 0, stream>>>(x, xf, xfT, Wa, ba, AW, X1h, X1l);
    proj_y<<<128, 256, 0, stream>>>(X1h, X1l, xf, pwf, nwf, PWb, NWb, y);
    bn_partial<<<64, 256, 0, stream>>>(y, part);
    bn_final<<<1, 256, 0, stream>>>(part, gamma, beta, stats);
    bn_apply<<<128, 256, 0, stream>>>(y, stats);
}